// Round 15
// baseline (200.222 us; speedup 1.0000x reference)
//
#include <hip/hip_runtime.h>
#include <stdint.h>

#define T_ 2048
#define E_ 1024

typedef __attribute__((ext_vector_type(8))) __bf16 bf16x8;
typedef __attribute__((ext_vector_type(4))) float f32x4;

__device__ __forceinline__ void gload_lds16(const void* g, void* l) {
  __builtin_amdgcn_global_load_lds(
      (const __attribute__((address_space(1))) unsigned int*)g,
      (__attribute__((address_space(3))) unsigned int*)l, 16, 0, 0);
}

// ---------------- fused prep: hi/lo splits + wout cvt + cos/sin table ----------------
// NOTE (R13 failure): in_proj weights MUST keep the hi/lo split. in_proj_weight is
// uniform [0,1) UNSCALED -> q,k are O(30-100), scores O(100): dropping Xh*Wl gives
// O(1) absolute score error which exp() turns into ~2x attention-weight distortion.
__global__ __launch_bounds__(256) void k_prep(const float4* __restrict__ q,
                                              ushort4* __restrict__ xh,
                                              ushort4* __restrict__ xl,
                                              const float4* __restrict__ win,
                                              ushort4* __restrict__ whh,
                                              ushort4* __restrict__ whl,
                                              const float4* __restrict__ wout,
                                              ushort4* __restrict__ wob,
                                              float2* __restrict__ cs) {
  const int b = blockIdx.x, tid = threadIdx.x;
  if (b < 7168) {  // hi/lo split: query (4096 blocks) then in_proj weights (3072)
    const float4* src;
    ushort4 *hi, *lo;
    int i;
    if (b < 4096) { src = q; hi = xh; lo = xl; i = b * 256 + tid; }
    else          { src = win; hi = whh; lo = whl; i = (b - 4096) * 256 + tid; }
    float4 x = src[i];
    float xs[4] = {x.x, x.y, x.z, x.w};
    union { __bf16 bb[4]; ushort4 u; } H, L;
#pragma unroll
    for (int jj = 0; jj < 4; ++jj) {
      __bf16 h = (__bf16)xs[jj];
      H.bb[jj] = h;
      L.bb[jj] = (__bf16)(xs[jj] - (float)h);
    }
    hi[i] = H.u;
    lo[i] = L.u;
  } else if (b < 8192) {  // wout plain cvt (1024 blocks)
    int i = (b - 7168) * 256 + tid;
    float4 x = wout[i];
    float xs[4] = {x.x, x.y, x.z, x.w};
    union { __bf16 bb[4]; ushort4 u; } H;
#pragma unroll
    for (int jj = 0; jj < 4; ++jj) H.bb[jj] = (__bf16)xs[jj];
    wob[i] = H.u;
  } else {  // cos/sin table, double precision (128 blocks)
    int i = (b - 8192) * 256 + tid;
    int t = i >> 4, f = i & 15;
    double inv = pow(10000.0, -(double)f / 16.0);
    double ang = (double)t * inv;
    cs[i] = make_float2((float)cos(ang), (float)sin(ang));
  }
}

// ---------------- merged projections: qk (blocks 0..511) + v (blocks 512..1023) ----
// NEW (R14->R15): DOUBLE-BUFFERED BK=32 pipeline — the k_attn-proven 1-barrier
// loop (prefetch step t+1 into buf[cur^1] BEFORE computing buf[cur]). Barrier
// count unchanged (32x1 vs 16x2), but the per-step L2/HBM drain now overlaps a
// full compute phase. The prior single-buffered 2-barrier structure exposed the
// drain every K-step (~45% neither-pipe-idle; only 2 blocks/CU of implicit
// overlap). LDS: 4 arrays x 2 bufs x 8KB = 64KB -> still 2 blocks/CU.
// BK=32 granule swizzle validated conflict-free in R10 (SQ_LDS_BANK_CONFLICT=0):
// store slot s of row r holds source granule s^((r>>1)&3); read rg=(g^((d>>1)&3))*8.
// qk: C(4096,2048) = X*W^T, 128x128 tile, hi/lo 3-term; fused RoPE + q-scale +
// hi/lo split out. XCD swizzle: i%8 = y>>2.
// v:  C(4096,1024) = X*Wv^T, 64x128 tile; fused transposed write to v16t.
// XCD swizzle: i%8 = y>>3 (bi%8 invariant: 512%8=0).
__global__ __launch_bounds__(256) void k_proj(const __bf16* __restrict__ xh,
                                              const __bf16* __restrict__ xl,
                                              const __bf16* __restrict__ whh,
                                              const __bf16* __restrict__ whl,
                                              const float2* __restrict__ cs,
                                              __bf16* __restrict__ qhi,
                                              __bf16* __restrict__ qlo,
                                              __bf16* __restrict__ khi,
                                              __bf16* __restrict__ klo,
                                              __bf16* __restrict__ v16t) {
  __shared__ __align__(16) __bf16 AsH[2][128 * 32];
  __shared__ __align__(16) __bf16 AsL[2][128 * 32];
  __shared__ __align__(16) __bf16 BsH[2][128 * 32];
  __shared__ __align__(16) __bf16 BsL[2][128 * 32];
  const int tid = threadIdx.x, lane = tid & 63, w = tid >> 6;
  const int g = lane >> 4, d = lane & 15;
  const int row0 = tid >> 2;                            // 0..63
  const int row1 = 64 + row0;
  const int sw32 = ((tid & 3) ^ ((tid >> 3) & 3)) * 8;  // src granule swizzle (R10-validated)
  const int rg = (g ^ ((d >> 1) & 3)) * 8;              // read granule swizzle
  const int K = 1024;

  if (blockIdx.x < 512) {  // ---- qk path ----
    const int bi = blockIdx.x;                  // i = (y>>2) + 8*x + 128*(y&3)
    const int bx = (bi >> 3) & 15;
    const int by = ((bi & 7) << 2) | ((bi >> 7) & 3);
    const int wm = w >> 1, wn = w & 1;
    const int m0 = by * 128, n0 = bx * 128;

    f32x4 acc[4][4];
#pragma unroll
    for (int i = 0; i < 4; ++i)
#pragma unroll
      for (int j = 0; j < 4; ++j) acc[i][j] = (f32x4)(0.0f);

#define STAGEQK(ks_, bb)                                                                  \
  {                                                                                       \
    const int kk = (ks_) * 32;                                                            \
    gload_lds16(xh + (size_t)(m0 + row0) * K + kk + sw32, &AsH[bb][w * 512]);             \
    gload_lds16(xh + (size_t)(m0 + row1) * K + kk + sw32, &AsH[bb][2048 + w * 512]);      \
    gload_lds16(xl + (size_t)(m0 + row0) * K + kk + sw32, &AsL[bb][w * 512]);             \
    gload_lds16(xl + (size_t)(m0 + row1) * K + kk + sw32, &AsL[bb][2048 + w * 512]);      \
    gload_lds16(whh + (size_t)(n0 + row0) * K + kk + sw32, &BsH[bb][w * 512]);            \
    gload_lds16(whh + (size_t)(n0 + row1) * K + kk + sw32, &BsH[bb][2048 + w * 512]);     \
    gload_lds16(whl + (size_t)(n0 + row0) * K + kk + sw32, &BsL[bb][w * 512]);            \
    gload_lds16(whl + (size_t)(n0 + row1) * K + kk + sw32, &BsL[bb][2048 + w * 512]);     \
  }

    int cur = 0;
    STAGEQK(0, 0);
    for (int ks = 0; ks < 32; ++ks) {
      __syncthreads();  // drains prefetch into buf[cur]; all waves done with buf[cur^1]
      if (ks < 31) STAGEQK(ks + 1, cur ^ 1);
      bf16x8 bh[4], bl[4];
#pragma unroll
      for (int j = 0; j < 4; ++j) {
        const int r = wn * 64 + j * 16 + d;
        bh[j] = *(const bf16x8*)&BsH[cur][r * 32 + rg];
        bl[j] = *(const bf16x8*)&BsL[cur][r * 32 + rg];
      }
#pragma unroll
      for (int i = 0; i < 4; ++i) {
        const int r = wm * 64 + i * 16 + d;
        const bf16x8 ahf = *(const bf16x8*)&AsH[cur][r * 32 + rg];
        const bf16x8 alf = *(const bf16x8*)&AsL[cur][r * 32 + rg];
#pragma unroll
        for (int j = 0; j < 4; ++j) {
          acc[i][j] = __builtin_amdgcn_mfma_f32_16x16x32_bf16(ahf, bh[j], acc[i][j], 0, 0, 0);
          acc[i][j] = __builtin_amdgcn_mfma_f32_16x16x32_bf16(alf, bh[j], acc[i][j], 0, 0, 0);
          acc[i][j] = __builtin_amdgcn_mfma_f32_16x16x32_bf16(ahf, bl[j], acc[i][j], 0, 0, 0);
        }
      }
      cur ^= 1;
    }
#undef STAGEQK

#pragma unroll
    for (int i = 0; i < 4; ++i) {
      const int rbase = m0 + wm * 64 + i * 16 + g * 4;
#pragma unroll
      for (int j = 0; j < 4; ++j) {
        const int col = n0 + wn * 64 + j * 16 + d;
#pragma unroll
        for (int r = 0; r < 4; ++r) {
          const float vv = acc[i][j][r];
          const int row = rbase + r;
          // RoPE pair partner (cl^1) lives at lane^1, same fragment reg
          const float xp = __shfl_xor(vv, 1);
          const int which = col >> 10;  // 0=q, 1=k
          const int cl = col & 1023;
          const int d2 = cl & 63;
          const int t2 = (row & 127) * 16 + (cl >> 6);  // reshaped position
          float y;
          if (d2 < 32) {
            const float2 cse = cs[t2 * 16 + (d2 >> 1)];
            y = (d2 & 1) ? (vv * cse.x + xp * cse.y) : (vv * cse.x - xp * cse.y);
          } else {
            y = vv;
          }
          if (which == 0) y *= 0.18033688011112042f;  // log2(e)/8: log2-domain scores
          const __bf16 hi = (__bf16)y;
          const __bf16 lo = (__bf16)(y - (float)hi);
          const size_t off = (size_t)row * 1024 + cl;  // flat == [panel][t2][d2]
          (which ? khi : qhi)[off] = hi;
          (which ? klo : qlo)[off] = lo;
        }
      }
    }
  } else {  // ---- v path (A in AsH rows 0..63, B in BsH; AsL/BsL unused) ----
    const int bi = blockIdx.x - 512;            // i = (y>>3) + 8*x + 64*(y&7)
    const int bx = (bi >> 3) & 7;
    const int by = ((bi & 7) << 3) | ((bi >> 6) & 7);
    const int m0 = by * 64, n0 = bx * 128;
    const __bf16* Bv = whh + (size_t)2048 * 1024;

    f32x4 acc[4][2];
#pragma unroll
    for (int i = 0; i < 4; ++i)
#pragma unroll
      for (int j = 0; j < 2; ++j) acc[i][j] = (f32x4)(0.0f);

#define STAGEV(ks_, bb)                                                                   \
  {                                                                                       \
    const int kk = (ks_) * 32;                                                            \
    gload_lds16(xh + (size_t)(m0 + row0) * K + kk + sw32, &AsH[bb][w * 512]);             \
    gload_lds16(Bv + (size_t)(n0 + row0) * K + kk + sw32, &BsH[bb][w * 512]);             \
    gload_lds16(Bv + (size_t)(n0 + row1) * K + kk + sw32, &BsH[bb][2048 + w * 512]);      \
  }

    int cur = 0;
    STAGEV(0, 0);
    for (int ks = 0; ks < 32; ++ks) {
      __syncthreads();
      if (ks < 31) STAGEV(ks + 1, cur ^ 1);
      bf16x8 bh[2], ah[4];
#pragma unroll
      for (int j = 0; j < 2; ++j)
        bh[j] = *(const bf16x8*)&BsH[cur][(w * 32 + j * 16 + d) * 32 + rg];
#pragma unroll
      for (int i = 0; i < 4; ++i)
        ah[i] = *(const bf16x8*)&AsH[cur][(i * 16 + d) * 32 + rg];
#pragma unroll
      for (int i = 0; i < 4; ++i)
#pragma unroll
        for (int j = 0; j < 2; ++j)
          acc[i][j] = __builtin_amdgcn_mfma_f32_16x16x32_bf16(ah[i], bh[j], acc[i][j], 0, 0, 0);
      cur ^= 1;
    }
#undef STAGEV

#pragma unroll
    for (int i = 0; i < 4; ++i) {
      const int rbase = m0 + i * 16 + g * 4;
#pragma unroll
      for (int j = 0; j < 2; ++j) {
        const int col = n0 + w * 32 + j * 16 + d;
#pragma unroll
        for (int r = 0; r < 4; ++r) {
          const int row = rbase + r;
          const int p = row >> 7;
          const int tp = ((row & 127) << 4) | (col >> 6);
          const int dp = col & 63;
          v16t[((size_t)p * 64 + dp) * 2048 + tp] = (__bf16)acc[i][j][r];
        }
      }
    }
  }
}

// ---------------- out projection GEMM, 32x128 tile, BK=64, grid 1024 ----------------
__global__ __launch_bounds__(256) void k_gemmout(const __bf16* __restrict__ Ah,
                                                 const __bf16* __restrict__ Bh,
                                                 float* __restrict__ C32) {
  __shared__ __align__(16) __bf16 As[32 * 64];
  __shared__ __align__(16) __bf16 Bs[128 * 64];
  const int bi = blockIdx.x;                    // bi = (by>>4) + 8*bx + 64*(by&15)
  const int bx = (bi >> 3) & 7;
  const int by = ((bi & 7) << 4) | (bi >> 6);
  const int tid = threadIdx.x, lane = tid & 63, w = tid >> 6;
  const int g = lane >> 4, d = lane & 15;
  const int m0 = by * 32, n0 = bx * 128;
  const int K = 1024, N = 1024;

  f32x4 acc[2][2];
#pragma unroll
  for (int i = 0; i < 2; ++i)
#pragma unroll
    for (int j = 0; j < 2; ++j) acc[i][j] = (f32x4)(0.0f);

  const int lr8 = lane >> 3;
  const int swz8 = ((lane & 7) ^ lr8) * 8;
  const int rsl = d & 7;

  for (int k0 = 0; k0 < K; k0 += 64) {
    __syncthreads();
    gload_lds16(Ah + (size_t)(m0 + w * 8 + lr8) * K + k0 + swz8, &As[(w * 8) * 64]);
#pragma unroll
    for (int c = 0; c < 4; ++c) {
      const int rr = c * 32 + w * 8 + lr8;
      gload_lds16(Bh + (size_t)(n0 + rr) * K + k0 + swz8, &Bs[(c * 32 + w * 8) * 64]);
    }
    __syncthreads();
#pragma unroll
    for (int k2 = 0; k2 < 2; ++k2) {
      const int sl = ((k2 * 4 + g) ^ rsl) * 8;
      bf16x8 bh[2], ah[2];
#pragma unroll
      for (int j = 0; j < 2; ++j)
        bh[j] = *(const bf16x8*)&Bs[(w * 32 + j * 16 + d) * 64 + sl];
#pragma unroll
      for (int i = 0; i < 2; ++i)
        ah[i] = *(const bf16x8*)&As[(i * 16 + d) * 64 + sl];
#pragma unroll
      for (int i = 0; i < 2; ++i)
#pragma unroll
        for (int j = 0; j < 2; ++j)
          acc[i][j] = __builtin_amdgcn_mfma_f32_16x16x32_bf16(ah[i], bh[j], acc[i][j], 0, 0, 0);
    }
  }

#pragma unroll
  for (int i = 0; i < 2; ++i) {
    const int rbase = m0 + i * 16 + g * 4;
#pragma unroll
    for (int j = 0; j < 2; ++j) {
      const int col = n0 + w * 32 + j * 16 + d;
#pragma unroll
      for (int r = 0; r < 4; ++r)
        C32[(size_t)(rbase + r) * N + col] = acc[i][j][r];
    }
  }
}

// ---------------- causal flash attention ----------------
// 512 thr / 8 waves; QBLK=256; KVBLK=64; double-buffered K/V, 1 barrier/tile.
// Equal-tile packing: 144 units/panel, 16 blocks x 9 units; <=2 segments/block;
// slot = b+qt (23/panel). Full-range segments (qt0) write x16 directly.
// XCD swizzle: panel%8 = i%8 (KV L2-resident, proven: FETCH 77->43MB).
// PL-LDS softmax->PV path (proven; in-register shuffle variant was buggy+costly).
__global__ __launch_bounds__(512, 4) void k_attn(const __bf16* __restrict__ qhi,
                                                 const __bf16* __restrict__ qlo,
                                                 const __bf16* __restrict__ khi,
                                                 const __bf16* __restrict__ klo,
                                                 const __bf16* __restrict__ v16t,
                                                 __bf16* __restrict__ x16,
                                                 float* __restrict__ po,
                                                 float* __restrict__ pm,
                                                 float* __restrict__ pl_) {
  __shared__ __align__(16) __bf16 KH[2][64 * 64];
  __shared__ __align__(16) __bf16 KL[2][64 * 64];
  __shared__ __align__(16) __bf16 VT[2][64 * 64];
  __shared__ __align__(16) __bf16 PL[8][16 * 72];

  const int bi = blockIdx.x;                    // i = (panel&7) + 8*b + 128*(panel>>3)
  const int b = (bi >> 3) & 15;
  const int panel = (bi & 7) | (((bi >> 7) & 3) << 3);
  const int u0 = 9 * b;
  int qtA = 0;
  while (2 * (qtA + 1) * (qtA + 2) <= u0) ++qtA;
  const int cumA = 2 * qtA * (qtA + 1);
  const int cumB = 2 * (qtA + 1) * (qtA + 2);
  const int jloA = u0 - cumA;
  const bool two = (u0 + 9 > cumB);
  const int jhiA = two ? (cumB - 1 - cumA) : (u0 + 8 - cumA);
  const int jhiB = u0 + 8 - cumB;  // valid only if two

  const int tid = threadIdx.x, lane = tid & 63, w = tid >> 6;
  const int g = lane >> 4, d = lane & 15;
  const size_t hb = (size_t)panel * T_ * 64;

  const int kr = tid >> 3, kc = tid & 7;
  const int swz = (kc ^ (kr & 7)) * 8;
  const __bf16* kB = khi + hb;
  const __bf16* lB = klo + hb;
  const __bf16* vB = v16t + (size_t)panel * (64 * T_);

#define STAGE(j, bb)                                                        \
  {                                                                         \
    gload_lds16(kB + (size_t)((j) * 64 + kr) * 64 + swz, &KH[bb][w * 512]); \
    gload_lds16(lB + (size_t)((j) * 64 + kr) * 64 + swz, &KL[bb][w * 512]); \
    gload_lds16(vB + (size_t)kr * T_ + (j) * 64 + swz, &VT[bb][w * 512]);   \
  }

  int cur = 0;
  STAGE(jloA, 0);

  for (int seg = 0; seg < 2; ++seg) {
    if (seg && !two) break;
    const int qt = qtA + seg;
    const int jlo = seg ? 0 : jloA;
    const int jhi = seg ? jhiB : jhiA;
    const int q0 = qt << 8;

    bf16x8 qh[2][2], ql[2][2];
#pragma unroll
    for (int rb = 0; rb < 2; ++rb) {
      const int rbi = w * 2 + rb;
      const size_t qrow = hb + (size_t)(q0 + rbi * 16 + d) * 64;
      qh[rb][0] = *(const bf16x8*)&qhi[qrow + g * 8];
      qh[rb][1] = *(const bf16x8*)&qhi[qrow + 32 + g * 8];
      ql[rb][0] = *(const bf16x8*)&qlo[qrow + g * 8];
      ql[rb][1] = *(const bf16x8*)&qlo[qrow + 32 + g * 8];
    }

    f32x4 o[2][4];
#pragma unroll
    for (int rb = 0; rb < 2; ++rb)
#pragma unroll
      for (int i = 0; i < 4; ++i) o[rb][i] = (f32x4)(0.0f);
    float m_[2] = {-__builtin_inff(), -__builtin_inff()};
    float l_[2] = {0.0f, 0.0f};

    for (int j = jlo; j <= jhi; ++j) {
      __syncthreads();  // drains prefetch into buf[cur]; frees buf[cur^1]
      if (j < jhi) {
        STAGE(j + 1, cur ^ 1);
      } else if (!seg && two) {
        STAGE(0, cur ^ 1);  // cross-segment prefetch (K/V depend only on j)
      }

#pragma unroll
      for (int rb = 0; rb < 2; ++rb) {
        const int rbi = w * 2 + rb;
        const int qrow0 = q0 + rbi * 16;
        if (j * 64 > qrow0 + 15) continue;  // fully masked rb: skip (partials stay safe)

        f32x4 s[4];
        __builtin_amdgcn_s_setprio(1);
#pragma unroll
        for (int f = 0; f < 4; ++f) {
          f32x4 accs = (f32x4)(0.0f);
          const int colr = f * 16 + d;
#pragma unroll
          for (int ds = 0; ds < 2; ++ds) {
            const int slot = ((ds * 4 + g) ^ (colr & 7)) * 8;
            const bf16x8 kf = *(const bf16x8*)&KH[cur][colr * 64 + slot];
            const bf16x8 lf = *(const bf16x8*)&KL[cur][colr * 64 + slot];
            // SWAPPED: S^T[kv][q] — K is the A-operand, Q the B-operand
            accs = __builtin_amdgcn_mfma_f32_16x16x32_bf16(kf, qh[rb][ds], accs, 0, 0, 0);
            accs = __builtin_amdgcn_mfma_f32_16x16x32_bf16(kf, ql[rb][ds], accs, 0, 0, 0);
            accs = __builtin_amdgcn_mfma_f32_16x16x32_bf16(lf, qh[rb][ds], accs, 0, 0, 0);
          }
          s[f] = accs;
        }
        __builtin_amdgcn_s_setprio(0);

        if (j * 64 + 63 > qrow0) {  // diagonal-crossing tile: mask kv > q
          const int qq = qrow0 + d;
#pragma unroll
          for (int f = 0; f < 4; ++f)
#pragma unroll
            for (int r = 0; r < 4; ++r) {
              const int kv = j * 64 + f * 16 + g * 4 + r;
              if (kv > qq) s[f][r] = -30000.0f;  // sentinel (log2 domain), NaN-safe
            }
        }

        // in-register softmax: lane owns q-row d; reduce in-lane + across g
        float pmax = fmaxf(fmaxf(s[0][0], s[0][1]), fmaxf(s[0][2], s[0][3]));
#pragma unroll
        for (int f = 1; f < 4; ++f)
          pmax = fmaxf(pmax, fmaxf(fmaxf(s[f][0], s[f][1]), fmaxf(s[f][2], s[f][3])));
        pmax = fmaxf(pmax, __shfl_xor(pmax, 16));
        pmax = fmaxf(pmax, __shfl_xor(pmax, 32));

        if (!__all(pmax - m_[rb] <= 11.5f)) {  // defer-max: rescale only on real growth
          const float mnew = fmaxf(m_[rb], pmax);
          const float fac = exp2f(m_[rb] - mnew);
          m_[rb] = mnew;
          float facr[4];
#pragma unroll
          for (int r = 0; r < 4; ++r)
            facr[r] = __shfl(fac, (lane & 48) | (g * 4 + r));  // fac for o-row g*4+r
#pragma unroll
          for (int ni = 0; ni < 4; ++ni)
#pragma unroll
            for (int r = 0; r < 4; ++r) o[rb][ni][r] *= facr[r];
          l_[rb] *= fac;
        }

        float sum = 0.0f;
#pragma unroll
        for (int f = 0; f < 4; ++f) {
          union { __bf16 bb[4]; ushort4 u4; } pk;
#pragma unroll
          for (int r = 0; r < 4; ++r) {
            const float pv = exp2f(s[f][r] - m_[rb]);
            sum += pv;
            pk.bb[r] = (__bf16)pv;
          }
          // P[q=d][kv=f*16+g*4 .. +4] packed: one ds_write_b64
          *(ushort4*)&PL[w][d * 72 + f * 16 + g * 4] = pk.u4;
        }
        sum += __shfl_xor(sum, 16);
        sum += __shfl_xor(sum, 32);
        l_[rb] += sum;

        __builtin_amdgcn_s_setprio(1);
#pragma unroll
        for (int ks = 0; ks < 2; ++ks) {
          const bf16x8 pa = *(const bf16x8*)&PL[w][d * 72 + ks * 32 + g * 8];
#pragma unroll
          for (int ni = 0; ni < 4; ++ni) {
            const bf16x8 vf =
                *(const bf16x8*)&VT[cur][(ni * 16 + d) * 64 + (((ks * 4 + g) ^ (d & 7)) * 8)];
            o[rb][ni] = __builtin_amdgcn_mfma_f32_16x16x32_bf16(pa, vf, o[rb][ni], 0, 0, 0);
          }
        }
        __builtin_amdgcn_s_setprio(0);
      }
      cur ^= 1;
    }

    if (jlo == 0 && jhi == 4 * qt + 3) {
      // segment covers the q-tile's full kv range: final write, no partials.
#pragma unroll
      for (int rb = 0; rb < 2; ++rb) {
        const int rbi = w * 2 + rb;
        float lr[4];
#pragma unroll
        for (int r = 0; r < 4; ++r)
          lr[r] = __shfl(l_[rb], (lane & 48) | (g * 4 + r));
#pragma unroll
        for (int ni = 0; ni < 4; ++ni)
#pragma unroll
          for (int r = 0; r < 4; ++r) {
            const size_t row = hb + (size_t)(q0 + rbi * 16 + g * 4 + r) * 64;
            x16[row + ni * 16 + d] = (__bf16)(o[rb][ni][r] / lr[r]);
          }
      }
    } else {
      const int slot = panel * 23 + b + qt;
#pragma unroll
      for (int rb = 0; rb < 2; ++rb) {
        const int rbi = w * 2 + rb;
#pragma unroll
        for (int ni = 0; ni < 4; ++ni)
#pragma unroll
          for (int r = 0; r < 4; ++r) {
            const int rowin = rbi * 16 + g * 4 + r;
            po[(size_t)slot * 16384 + rowin * 64 + ni * 16 + d] = o[rb][ni][r];
          }
        if (g == 0) {  // lane owns q-row d: one write per row
          pm[slot * 256 + rbi * 16 + d] = m_[rb];
          pl_[slot * 256 + rbi * 16 + d] = l_[rb];
        }
      }
    }
  }
#undef STAGE
}

// ---------------- merge KV-chunk partials for rows 256..2047 (log2 domain) ----------------
// 1D grid 14336, XCD-aligned: panel%8 == bi%8 matches attn's panel->XCD map so
// po/pm/pl reads hit the L2 that produced them.
__global__ __launch_bounds__(256) void k_combine(const float* __restrict__ po,
                                                 const float* __restrict__ pm,
                                                 const float* __restrict__ pl_,
                                                 __bf16* __restrict__ x16) {
  const int bi = blockIdx.x;                      // 8 * 448 * 4
  const int p = (bi & 7) | ((bi / 3584) << 3);
  const int li = ((bi >> 3) % 448) * 256 + threadIdx.x;
  const int d = li & 63;
  const int t2 = 256 + (li >> 6);
  const int qt = t2 >> 8;                          // 1..7
  const int rowin = t2 & 255;
  const int cq = 2 * qt * (qt + 1);
  const int nc = (cq + 4 * qt + 3) / 9 - cq / 9 + 1;
  const int s0 = p * 23 + cq / 9 + qt;
  float M = -__builtin_inff();
  for (int s = 0; s < nc; ++s) M = fmaxf(M, pm[(s0 + s) * 256 + rowin]);
  float L = 0.0f, O = 0.0f;
  for (int s = 0; s < nc; ++s) {
    const float ww = exp2f(pm[(s0 + s) * 256 + rowin] - M);
    L += pl_[(s0 + s) * 256 + rowin] * ww;
    O += po[(size_t)(s0 + s) * 16384 + rowin * 64 + d] * ww;
  }
  x16[((size_t)p * T_ + t2) * 64 + d] = (__bf16)(O / L);
}

extern "C" void kernel_launch(void* const* d_in, const int* in_sizes, int n_in,
                              void* d_out, int out_size, void* d_ws, size_t ws_size,
                              hipStream_t stream) {
  const float* query = (const float*)d_in[0];
  const float* win = (const float*)d_in[4];
  const float* wout = (const float*)d_in[5];
  float* out = (float*)d_out;

  const size_t MB = 1024 * 1024;
  const size_t KB = 1024;
  char* ws = (char*)d_ws;
  // Lifetime plan: prep buffers (0-28) die after k_proj; po (attn-write) overlays
  // them at 0-46. v16t at 46-54 (written by k_proj v-path concurrently with
  // qk-path reads of 0-28 -> disjoint). Peak usage 89.75 MB.
  __bf16* xh = (__bf16*)(ws);                    // 0-8
  __bf16* xl = (__bf16*)(ws + 8 * MB);           // 8-16
  __bf16* whh = (__bf16*)(ws + 16 * MB);         // 16-22
  __bf16* whl = (__bf16*)(ws + 22 * MB);         // 22-28
  float* po = (float*)(ws);                      // 0-46 (attn-write, prep bufs dead)
  __bf16* v16t = (__bf16*)(ws + 46 * MB);        // 46-54
  __bf16* qhi = (__bf16*)(ws + 54 * MB);         // 54-62
  __bf16* qlo = (__bf16*)(ws + 62 * MB);         // 62-70
  __bf16* khi = (__bf16*)(ws + 70 * MB);         // 70-78
  __bf16* klo = (__bf16*)(ws + 78 * MB);         // 78-86
  __bf16* wob = (__bf16*)(ws + 86 * MB);         // 86-88
  float* pm = (float*)(ws + 88 * MB);            // 88-88.72
  float* pl_ = (float*)(ws + 88 * MB + 768 * KB);
  float2* cs = (float2*)(ws + 89 * MB + 512 * KB);  // 256 KB
  __bf16* x16 = (__bf16*)(ws + 54 * MB);         // alias qhi (dead after k_attn)

  k_prep<<<8320, 256, 0, stream>>>((const float4*)query, (ushort4*)xh, (ushort4*)xl,
                                   (const float4*)win, (ushort4*)whh, (ushort4*)whl,
                                   (const float4*)wout, (ushort4*)wob, cs);

  // merged q,k,v projections (double-buffered BK=32 pipeline)
  k_proj<<<1024, 256, 0, stream>>>(xh, xl, whh, whl, cs, qhi, qlo, khi, klo, v16t);

  // causal flash attention (XCD-swizzled flat grid)
  k_attn<<<512, 512, 0, stream>>>(qhi, qlo, khi, klo, v16t, x16, po, pm, pl_);

  // combine (XCD-aligned to attn's panel map)
  k_combine<<<14336, 256, 0, stream>>>(po, pm, pl_, x16);

  // out projection (32x128 tiles, grid 1024 -> 4 blocks/CU)
  k_gemmout<<<1024, 256, 0, stream>>>(x16, wob, out);
}

// Round 16
// 186.198 us; speedup vs baseline: 1.0753x; 1.0753x over previous
//
#include <hip/hip_runtime.h>
#include <stdint.h>

#define T_ 2048
#define E_ 1024

typedef __attribute__((ext_vector_type(8))) __bf16 bf16x8;
typedef __attribute__((ext_vector_type(4))) float f32x4;

__device__ __forceinline__ void gload_lds16(const void* g, void* l) {
  __builtin_amdgcn_global_load_lds(
      (const __attribute__((address_space(1))) unsigned int*)g,
      (__attribute__((address_space(3))) unsigned int*)l, 16, 0, 0);
}

// ---------------- fused prep: hi/lo splits + wout cvt + cos/sin table ----------------
// NOTE (R13): in_proj weights MUST keep the hi/lo split (q,k are O(30-100),
// scores O(100); dropping Xh*Wl -> O(1) absolute score error -> exp blows it up).
__global__ __launch_bounds__(256) void k_prep(const float4* __restrict__ q,
                                              ushort4* __restrict__ xh,
                                              ushort4* __restrict__ xl,
                                              const float4* __restrict__ win,
                                              ushort4* __restrict__ whh,
                                              ushort4* __restrict__ whl,
                                              const float4* __restrict__ wout,
                                              ushort4* __restrict__ wob,
                                              float2* __restrict__ cs) {
  const int b = blockIdx.x, tid = threadIdx.x;
  if (b < 7168) {  // hi/lo split: query (4096 blocks) then in_proj weights (3072)
    const float4* src;
    ushort4 *hi, *lo;
    int i;
    if (b < 4096) { src = q; hi = xh; lo = xl; i = b * 256 + tid; }
    else          { src = win; hi = whh; lo = whl; i = (b - 4096) * 256 + tid; }
    float4 x = src[i];
    float xs[4] = {x.x, x.y, x.z, x.w};
    union { __bf16 bb[4]; ushort4 u; } H, L;
#pragma unroll
    for (int jj = 0; jj < 4; ++jj) {
      __bf16 h = (__bf16)xs[jj];
      H.bb[jj] = h;
      L.bb[jj] = (__bf16)(xs[jj] - (float)h);
    }
    hi[i] = H.u;
    lo[i] = L.u;
  } else if (b < 8192) {  // wout plain cvt (1024 blocks)
    int i = (b - 7168) * 256 + tid;
    float4 x = wout[i];
    float xs[4] = {x.x, x.y, x.z, x.w};
    union { __bf16 bb[4]; ushort4 u; } H;
#pragma unroll
    for (int jj = 0; jj < 4; ++jj) H.bb[jj] = (__bf16)xs[jj];
    wob[i] = H.u;
  } else {  // cos/sin table, double precision (128 blocks)
    int i = (b - 8192) * 256 + tid;
    int t = i >> 4, f = i & 15;
    double inv = pow(10000.0, -(double)f / 16.0);
    double ang = (double)t * inv;
    cs[i] = make_float2((float)cos(ang), (float)sin(ang));
  }
}

// ---------------- merged projections: qk (blocks 0..511) + v (blocks 512..1023) ----
// ROUND-8/12/14 PROVEN OPTIMUM (76.4us, 898 TF ~ m97-class 2-barrier ceiling).
// Closed ledger of failed attacks: R9 512-thr (spill), R10 BK=32 single-buf
// (2x drains), R11 128x64 tiles (2x A-traffic), R13 2-term (correctness),
// R15 BK=32 dbuf (2x barrier drains — __syncthreads always emits vmcnt(0);
// MfmaUtil 33->25). Only remaining lever: 8-phase counted-vmcnt rewrite (T3+T4).
// qk: C(4096,2048) = X*W^T, 128x128 tile, BK=64, hi/lo 3-term; fused RoPE +
// q-scale + hi/lo split out. XCD swizzle: i%8 = y>>2.
// v:  C(4096,1024) = X*Wv^T, 64x128 tile, BK=64; fused transposed write to v16t.
// XCD swizzle: i%8 = y>>3 (bi%8 invariant: 512%8=0).
__global__ __launch_bounds__(256) void k_proj(const __bf16* __restrict__ xh,
                                              const __bf16* __restrict__ xl,
                                              const __bf16* __restrict__ whh,
                                              const __bf16* __restrict__ whl,
                                              const float2* __restrict__ cs,
                                              __bf16* __restrict__ qhi,
                                              __bf16* __restrict__ qlo,
                                              __bf16* __restrict__ khi,
                                              __bf16* __restrict__ klo,
                                              __bf16* __restrict__ v16t) {
  __shared__ __align__(16) __bf16 AsH[128 * 64];
  __shared__ __align__(16) __bf16 BsH[128 * 64];
  __shared__ __align__(16) __bf16 AsL[128 * 64];
  __shared__ __align__(16) __bf16 BsL[128 * 64];
  const int tid = threadIdx.x, lane = tid & 63, w = tid >> 6;
  const int g = lane >> 4, d = lane & 15;
  const int lr8 = lane >> 3;
  const int swz8 = ((lane & 7) ^ lr8) * 8;
  const int rsl = d & 7;
  const int K = 1024;

  if (blockIdx.x < 512) {  // ---- qk path ----
    const int bi = blockIdx.x;                  // i = (y>>2) + 8*x + 128*(y&3)
    const int bx = (bi >> 3) & 15;
    const int by = ((bi & 7) << 2) | ((bi >> 7) & 3);
    const int wm = w >> 1, wn = w & 1;
    const int m0 = by * 128, n0 = bx * 128;

    f32x4 acc[4][4];
#pragma unroll
    for (int i = 0; i < 4; ++i)
#pragma unroll
      for (int j = 0; j < 4; ++j) acc[i][j] = (f32x4)(0.0f);

    for (int k0 = 0; k0 < K; k0 += 64) {
      __syncthreads();
#pragma unroll
      for (int c = 0; c < 4; ++c) {
        const int rr = c * 32 + w * 8 + lr8;
        const int ldo = (c * 32 + w * 8) * 64;
        gload_lds16(xh + (size_t)(m0 + rr) * K + k0 + swz8, &AsH[ldo]);
        gload_lds16(xl + (size_t)(m0 + rr) * K + k0 + swz8, &AsL[ldo]);
        gload_lds16(whh + (size_t)(n0 + rr) * K + k0 + swz8, &BsH[ldo]);
        gload_lds16(whl + (size_t)(n0 + rr) * K + k0 + swz8, &BsL[ldo]);
      }
      __syncthreads();
#pragma unroll
      for (int k2 = 0; k2 < 2; ++k2) {
        const int sl = ((k2 * 4 + g) ^ rsl) * 8;
        bf16x8 bh[4], bl[4];
#pragma unroll
        for (int j = 0; j < 4; ++j) {
          const int r = wn * 64 + j * 16 + d;
          bh[j] = *(const bf16x8*)&BsH[r * 64 + sl];
          bl[j] = *(const bf16x8*)&BsL[r * 64 + sl];
        }
#pragma unroll
        for (int i = 0; i < 4; ++i) {
          const int r = wm * 64 + i * 16 + d;
          const bf16x8 ahf = *(const bf16x8*)&AsH[r * 64 + sl];
          const bf16x8 alf = *(const bf16x8*)&AsL[r * 64 + sl];
#pragma unroll
          for (int j = 0; j < 4; ++j) {
            acc[i][j] = __builtin_amdgcn_mfma_f32_16x16x32_bf16(ahf, bh[j], acc[i][j], 0, 0, 0);
            acc[i][j] = __builtin_amdgcn_mfma_f32_16x16x32_bf16(alf, bh[j], acc[i][j], 0, 0, 0);
            acc[i][j] = __builtin_amdgcn_mfma_f32_16x16x32_bf16(ahf, bl[j], acc[i][j], 0, 0, 0);
          }
        }
      }
    }

#pragma unroll
    for (int i = 0; i < 4; ++i) {
      const int rbase = m0 + (w >> 1) * 64 + i * 16 + g * 4;
#pragma unroll
      for (int j = 0; j < 4; ++j) {
        const int col = n0 + (w & 1) * 64 + j * 16 + d;
#pragma unroll
        for (int r = 0; r < 4; ++r) {
          const float vv = acc[i][j][r];
          const int row = rbase + r;
          // RoPE pair partner (cl^1) lives at lane^1, same fragment reg
          const float xp = __shfl_xor(vv, 1);
          const int which = col >> 10;  // 0=q, 1=k
          const int cl = col & 1023;
          const int d2 = cl & 63;
          const int t2 = (row & 127) * 16 + (cl >> 6);  // reshaped position
          float y;
          if (d2 < 32) {
            const float2 cse = cs[t2 * 16 + (d2 >> 1)];
            y = (d2 & 1) ? (vv * cse.x + xp * cse.y) : (vv * cse.x - xp * cse.y);
          } else {
            y = vv;
          }
          if (which == 0) y *= 0.18033688011112042f;  // log2(e)/8: log2-domain scores
          const __bf16 hi = (__bf16)y;
          const __bf16 lo = (__bf16)(y - (float)hi);
          const size_t off = (size_t)row * 1024 + cl;  // flat == [panel][t2][d2]
          (which ? khi : qhi)[off] = hi;
          (which ? klo : qlo)[off] = lo;
        }
      }
    }
  } else {  // ---- v path (uses AsH as As, BsH as Bs) ----
    const int bi = blockIdx.x - 512;            // i = (y>>3) + 8*x + 64*(y&7)
    const int bx = (bi >> 3) & 7;
    const int by = ((bi & 7) << 3) | ((bi >> 6) & 7);
    const int m0 = by * 64, n0 = bx * 128;
    const __bf16* Bv = whh + (size_t)2048 * 1024;

    f32x4 acc[4][2];
#pragma unroll
    for (int i = 0; i < 4; ++i)
#pragma unroll
      for (int j = 0; j < 2; ++j) acc[i][j] = (f32x4)(0.0f);

    for (int k0 = 0; k0 < K; k0 += 64) {
      __syncthreads();
#pragma unroll
      for (int c = 0; c < 2; ++c) {
        const int rr = c * 32 + w * 8 + lr8;
        gload_lds16(xh + (size_t)(m0 + rr) * K + k0 + swz8, &AsH[(c * 32 + w * 8) * 64]);
      }
#pragma unroll
      for (int c = 0; c < 4; ++c) {
        const int rr = c * 32 + w * 8 + lr8;
        gload_lds16(Bv + (size_t)(n0 + rr) * K + k0 + swz8, &BsH[(c * 32 + w * 8) * 64]);
      }
      __syncthreads();
#pragma unroll
      for (int k2 = 0; k2 < 2; ++k2) {
        const int sl = ((k2 * 4 + g) ^ rsl) * 8;
        bf16x8 bh[2], ah[4];
#pragma unroll
        for (int j = 0; j < 2; ++j)
          bh[j] = *(const bf16x8*)&BsH[(w * 32 + j * 16 + d) * 64 + sl];
#pragma unroll
        for (int i = 0; i < 4; ++i)
          ah[i] = *(const bf16x8*)&AsH[(i * 16 + d) * 64 + sl];
#pragma unroll
        for (int i = 0; i < 4; ++i)
#pragma unroll
          for (int j = 0; j < 2; ++j)
            acc[i][j] = __builtin_amdgcn_mfma_f32_16x16x32_bf16(ah[i], bh[j], acc[i][j], 0, 0, 0);
      }
    }

#pragma unroll
    for (int i = 0; i < 4; ++i) {
      const int rbase = m0 + i * 16 + g * 4;
#pragma unroll
      for (int j = 0; j < 2; ++j) {
        const int col = n0 + w * 32 + j * 16 + d;
#pragma unroll
        for (int r = 0; r < 4; ++r) {
          const int row = rbase + r;
          const int p = row >> 7;
          const int tp = ((row & 127) << 4) | (col >> 6);
          const int dp = col & 63;
          v16t[((size_t)p * 64 + dp) * 2048 + tp] = (__bf16)acc[i][j][r];
        }
      }
    }
  }
}

// ---------------- out projection GEMM, 32x128 tile, BK=64, grid 1024 ----------------
__global__ __launch_bounds__(256) void k_gemmout(const __bf16* __restrict__ Ah,
                                                 const __bf16* __restrict__ Bh,
                                                 float* __restrict__ C32) {
  __shared__ __align__(16) __bf16 As[32 * 64];
  __shared__ __align__(16) __bf16 Bs[128 * 64];
  const int bi = blockIdx.x;                    // bi = (by>>4) + 8*bx + 64*(by&15)
  const int bx = (bi >> 3) & 7;
  const int by = ((bi & 7) << 4) | (bi >> 6);
  const int tid = threadIdx.x, lane = tid & 63, w = tid >> 6;
  const int g = lane >> 4, d = lane & 15;
  const int m0 = by * 32, n0 = bx * 128;
  const int K = 1024, N = 1024;

  f32x4 acc[2][2];
#pragma unroll
  for (int i = 0; i < 2; ++i)
#pragma unroll
    for (int j = 0; j < 2; ++j) acc[i][j] = (f32x4)(0.0f);

  const int lr8 = lane >> 3;
  const int swz8 = ((lane & 7) ^ lr8) * 8;
  const int rsl = d & 7;

  for (int k0 = 0; k0 < K; k0 += 64) {
    __syncthreads();
    gload_lds16(Ah + (size_t)(m0 + w * 8 + lr8) * K + k0 + swz8, &As[(w * 8) * 64]);
#pragma unroll
    for (int c = 0; c < 4; ++c) {
      const int rr = c * 32 + w * 8 + lr8;
      gload_lds16(Bh + (size_t)(n0 + rr) * K + k0 + swz8, &Bs[(c * 32 + w * 8) * 64]);
    }
    __syncthreads();
#pragma unroll
    for (int k2 = 0; k2 < 2; ++k2) {
      const int sl = ((k2 * 4 + g) ^ rsl) * 8;
      bf16x8 bh[2], ah[2];
#pragma unroll
      for (int j = 0; j < 2; ++j)
        bh[j] = *(const bf16x8*)&Bs[(w * 32 + j * 16 + d) * 64 + sl];
#pragma unroll
      for (int i = 0; i < 2; ++i)
        ah[i] = *(const bf16x8*)&As[(i * 16 + d) * 64 + sl];
#pragma unroll
      for (int i = 0; i < 2; ++i)
#pragma unroll
        for (int j = 0; j < 2; ++j)
          acc[i][j] = __builtin_amdgcn_mfma_f32_16x16x32_bf16(ah[i], bh[j], acc[i][j], 0, 0, 0);
    }
  }

#pragma unroll
  for (int i = 0; i < 2; ++i) {
    const int rbase = m0 + i * 16 + g * 4;
#pragma unroll
    for (int j = 0; j < 2; ++j) {
      const int col = n0 + w * 32 + j * 16 + d;
#pragma unroll
      for (int r = 0; r < 4; ++r)
        C32[(size_t)(rbase + r) * N + col] = acc[i][j][r];
    }
  }
}

// ---------------- causal flash attention ----------------
// 512 thr / 8 waves; QBLK=256; KVBLK=64; double-buffered K/V, 1 barrier/tile.
// Equal-tile packing: 144 units/panel, 16 blocks x 9 units; <=2 segments/block;
// slot = b+qt (23/panel). Full-range segments (qt0) write x16 directly.
// XCD swizzle: panel%8 = i%8 (KV L2-resident, proven: FETCH 77->43MB).
// PL-LDS softmax->PV path (proven; in-register shuffle variant was buggy+costly).
__global__ __launch_bounds__(512, 4) void k_attn(const __bf16* __restrict__ qhi,
                                                 const __bf16* __restrict__ qlo,
                                                 const __bf16* __restrict__ khi,
                                                 const __bf16* __restrict__ klo,
                                                 const __bf16* __restrict__ v16t,
                                                 __bf16* __restrict__ x16,
                                                 float* __restrict__ po,
                                                 float* __restrict__ pm,
                                                 float* __restrict__ pl_) {
  __shared__ __align__(16) __bf16 KH[2][64 * 64];
  __shared__ __align__(16) __bf16 KL[2][64 * 64];
  __shared__ __align__(16) __bf16 VT[2][64 * 64];
  __shared__ __align__(16) __bf16 PL[8][16 * 72];

  const int bi = blockIdx.x;                    // i = (panel&7) + 8*b + 128*(panel>>3)
  const int b = (bi >> 3) & 15;
  const int panel = (bi & 7) | (((bi >> 7) & 3) << 3);
  const int u0 = 9 * b;
  int qtA = 0;
  while (2 * (qtA + 1) * (qtA + 2) <= u0) ++qtA;
  const int cumA = 2 * qtA * (qtA + 1);
  const int cumB = 2 * (qtA + 1) * (qtA + 2);
  const int jloA = u0 - cumA;
  const bool two = (u0 + 9 > cumB);
  const int jhiA = two ? (cumB - 1 - cumA) : (u0 + 8 - cumA);
  const int jhiB = u0 + 8 - cumB;  // valid only if two

  const int tid = threadIdx.x, lane = tid & 63, w = tid >> 6;
  const int g = lane >> 4, d = lane & 15;
  const size_t hb = (size_t)panel * T_ * 64;

  const int kr = tid >> 3, kc = tid & 7;
  const int swz = (kc ^ (kr & 7)) * 8;
  const __bf16* kB = khi + hb;
  const __bf16* lB = klo + hb;
  const __bf16* vB = v16t + (size_t)panel * (64 * T_);

#define STAGE(j, bb)                                                        \
  {                                                                         \
    gload_lds16(kB + (size_t)((j) * 64 + kr) * 64 + swz, &KH[bb][w * 512]); \
    gload_lds16(lB + (size_t)((j) * 64 + kr) * 64 + swz, &KL[bb][w * 512]); \
    gload_lds16(vB + (size_t)kr * T_ + (j) * 64 + swz, &VT[bb][w * 512]);   \
  }

  int cur = 0;
  STAGE(jloA, 0);

  for (int seg = 0; seg < 2; ++seg) {
    if (seg && !two) break;
    const int qt = qtA + seg;
    const int jlo = seg ? 0 : jloA;
    const int jhi = seg ? jhiB : jhiA;
    const int q0 = qt << 8;

    bf16x8 qh[2][2], ql[2][2];
#pragma unroll
    for (int rb = 0; rb < 2; ++rb) {
      const int rbi = w * 2 + rb;
      const size_t qrow = hb + (size_t)(q0 + rbi * 16 + d) * 64;
      qh[rb][0] = *(const bf16x8*)&qhi[qrow + g * 8];
      qh[rb][1] = *(const bf16x8*)&qhi[qrow + 32 + g * 8];
      ql[rb][0] = *(const bf16x8*)&qlo[qrow + g * 8];
      ql[rb][1] = *(const bf16x8*)&qlo[qrow + 32 + g * 8];
    }

    f32x4 o[2][4];
#pragma unroll
    for (int rb = 0; rb < 2; ++rb)
#pragma unroll
      for (int i = 0; i < 4; ++i) o[rb][i] = (f32x4)(0.0f);
    float m_[2] = {-__builtin_inff(), -__builtin_inff()};
    float l_[2] = {0.0f, 0.0f};

    for (int j = jlo; j <= jhi; ++j) {
      __syncthreads();  // drains prefetch into buf[cur]; frees buf[cur^1]
      if (j < jhi) {
        STAGE(j + 1, cur ^ 1);
      } else if (!seg && two) {
        STAGE(0, cur ^ 1);  // cross-segment prefetch (K/V depend only on j)
      }

#pragma unroll
      for (int rb = 0; rb < 2; ++rb) {
        const int rbi = w * 2 + rb;
        const int qrow0 = q0 + rbi * 16;
        if (j * 64 > qrow0 + 15) continue;  // fully masked rb: skip (partials stay safe)

        f32x4 s[4];
        __builtin_amdgcn_s_setprio(1);
#pragma unroll
        for (int f = 0; f < 4; ++f) {
          f32x4 accs = (f32x4)(0.0f);
          const int colr = f * 16 + d;
#pragma unroll
          for (int ds = 0; ds < 2; ++ds) {
            const int slot = ((ds * 4 + g) ^ (colr & 7)) * 8;
            const bf16x8 kf = *(const bf16x8*)&KH[cur][colr * 64 + slot];
            const bf16x8 lf = *(const bf16x8*)&KL[cur][colr * 64 + slot];
            // SWAPPED: S^T[kv][q] — K is the A-operand, Q the B-operand
            accs = __builtin_amdgcn_mfma_f32_16x16x32_bf16(kf, qh[rb][ds], accs, 0, 0, 0);
            accs = __builtin_amdgcn_mfma_f32_16x16x32_bf16(kf, ql[rb][ds], accs, 0, 0, 0);
            accs = __builtin_amdgcn_mfma_f32_16x16x32_bf16(lf, qh[rb][ds], accs, 0, 0, 0);
          }
          s[f] = accs;
        }
        __builtin_amdgcn_s_setprio(0);

        if (j * 64 + 63 > qrow0) {  // diagonal-crossing tile: mask kv > q
          const int qq = qrow0 + d;
#pragma unroll
          for (int f = 0; f < 4; ++f)
#pragma unroll
            for (int r = 0; r < 4; ++r) {
              const int kv = j * 64 + f * 16 + g * 4 + r;
              if (kv > qq) s[f][r] = -30000.0f;  // sentinel (log2 domain), NaN-safe
            }
        }

        // in-register softmax: lane owns q-row d; reduce in-lane + across g
        float pmax = fmaxf(fmaxf(s[0][0], s[0][1]), fmaxf(s[0][2], s[0][3]));
#pragma unroll
        for (int f = 1; f < 4; ++f)
          pmax = fmaxf(pmax, fmaxf(fmaxf(s[f][0], s[f][1]), fmaxf(s[f][2], s[f][3])));
        pmax = fmaxf(pmax, __shfl_xor(pmax, 16));
        pmax = fmaxf(pmax, __shfl_xor(pmax, 32));

        if (!__all(pmax - m_[rb] <= 11.5f)) {  // defer-max: rescale only on real growth
          const float mnew = fmaxf(m_[rb], pmax);
          const float fac = exp2f(m_[rb] - mnew);
          m_[rb] = mnew;
          float facr[4];
#pragma unroll
          for (int r = 0; r < 4; ++r)
            facr[r] = __shfl(fac, (lane & 48) | (g * 4 + r));  // fac for o-row g*4+r
#pragma unroll
          for (int ni = 0; ni < 4; ++ni)
#pragma unroll
            for (int r = 0; r < 4; ++r) o[rb][ni][r] *= facr[r];
          l_[rb] *= fac;
        }

        float sum = 0.0f;
#pragma unroll
        for (int f = 0; f < 4; ++f) {
          union { __bf16 bb[4]; ushort4 u4; } pk;
#pragma unroll
          for (int r = 0; r < 4; ++r) {
            const float pv = exp2f(s[f][r] - m_[rb]);
            sum += pv;
            pk.bb[r] = (__bf16)pv;
          }
          // P[q=d][kv=f*16+g*4 .. +4] packed: one ds_write_b64
          *(ushort4*)&PL[w][d * 72 + f * 16 + g * 4] = pk.u4;
        }
        sum += __shfl_xor(sum, 16);
        sum += __shfl_xor(sum, 32);
        l_[rb] += sum;

        __builtin_amdgcn_s_setprio(1);
#pragma unroll
        for (int ks = 0; ks < 2; ++ks) {
          const bf16x8 pa = *(const bf16x8*)&PL[w][d * 72 + ks * 32 + g * 8];
#pragma unroll
          for (int ni = 0; ni < 4; ++ni) {
            const bf16x8 vf =
                *(const bf16x8*)&VT[cur][(ni * 16 + d) * 64 + (((ks * 4 + g) ^ (d & 7)) * 8)];
            o[rb][ni] = __builtin_amdgcn_mfma_f32_16x16x32_bf16(pa, vf, o[rb][ni], 0, 0, 0);
          }
        }
        __builtin_amdgcn_s_setprio(0);
      }
      cur ^= 1;
    }

    if (jlo == 0 && jhi == 4 * qt + 3) {
      // segment covers the q-tile's full kv range: final write, no partials.
#pragma unroll
      for (int rb = 0; rb < 2; ++rb) {
        const int rbi = w * 2 + rb;
        float lr[4];
#pragma unroll
        for (int r = 0; r < 4; ++r)
          lr[r] = __shfl(l_[rb], (lane & 48) | (g * 4 + r));
#pragma unroll
        for (int ni = 0; ni < 4; ++ni)
#pragma unroll
          for (int r = 0; r < 4; ++r) {
            const size_t row = hb + (size_t)(q0 + rbi * 16 + g * 4 + r) * 64;
            x16[row + ni * 16 + d] = (__bf16)(o[rb][ni][r] / lr[r]);
          }
      }
    } else {
      const int slot = panel * 23 + b + qt;
#pragma unroll
      for (int rb = 0; rb < 2; ++rb) {
        const int rbi = w * 2 + rb;
#pragma unroll
        for (int ni = 0; ni < 4; ++ni)
#pragma unroll
          for (int r = 0; r < 4; ++r) {
            const int rowin = rbi * 16 + g * 4 + r;
            po[(size_t)slot * 16384 + rowin * 64 + ni * 16 + d] = o[rb][ni][r];
          }
        if (g == 0) {  // lane owns q-row d: one write per row
          pm[slot * 256 + rbi * 16 + d] = m_[rb];
          pl_[slot * 256 + rbi * 16 + d] = l_[rb];
        }
      }
    }
  }
#undef STAGE
}

// ---------------- merge KV-chunk partials for rows 256..2047 (log2 domain) ----------------
// 1D grid 14336, XCD-aligned: panel%8 == bi%8 matches attn's panel->XCD map so
// po/pm/pl reads hit the L2 that produced them.
__global__ __launch_bounds__(256) void k_combine(const float* __restrict__ po,
                                                 const float* __restrict__ pm,
                                                 const float* __restrict__ pl_,
                                                 __bf16* __restrict__ x16) {
  const int bi = blockIdx.x;                      // 8 * 448 * 4
  const int p = (bi & 7) | ((bi / 3584) << 3);
  const int li = ((bi >> 3) % 448) * 256 + threadIdx.x;
  const int d = li & 63;
  const int t2 = 256 + (li >> 6);
  const int qt = t2 >> 8;                          // 1..7
  const int rowin = t2 & 255;
  const int cq = 2 * qt * (qt + 1);
  const int nc = (cq + 4 * qt + 3) / 9 - cq / 9 + 1;
  const int s0 = p * 23 + cq / 9 + qt;
  float M = -__builtin_inff();
  for (int s = 0; s < nc; ++s) M = fmaxf(M, pm[(s0 + s) * 256 + rowin]);
  float L = 0.0f, O = 0.0f;
  for (int s = 0; s < nc; ++s) {
    const float ww = exp2f(pm[(s0 + s) * 256 + rowin] - M);
    L += pl_[(s0 + s) * 256 + rowin] * ww;
    O += po[(size_t)(s0 + s) * 16384 + rowin * 64 + d] * ww;
  }
  x16[((size_t)p * T_ + t2) * 64 + d] = (__bf16)(O / L);
}

extern "C" void kernel_launch(void* const* d_in, const int* in_sizes, int n_in,
                              void* d_out, int out_size, void* d_ws, size_t ws_size,
                              hipStream_t stream) {
  const float* query = (const float*)d_in[0];
  const float* win = (const float*)d_in[4];
  const float* wout = (const float*)d_in[5];
  float* out = (float*)d_out;

  const size_t MB = 1024 * 1024;
  const size_t KB = 1024;
  char* ws = (char*)d_ws;
  // Lifetime plan: prep buffers (0-28) die after k_proj; po (attn-write) overlays
  // them at 0-46. v16t at 46-54 (written by k_proj v-path concurrently with
  // qk-path reads of 0-28 -> disjoint). Peak usage 89.75 MB.
  __bf16* xh = (__bf16*)(ws);                    // 0-8
  __bf16* xl = (__bf16*)(ws + 8 * MB);           // 8-16
  __bf16* whh = (__bf16*)(ws + 16 * MB);         // 16-22
  __bf16* whl = (__bf16*)(ws + 22 * MB);         // 22-28
  float* po = (float*)(ws);                      // 0-46 (attn-write, prep bufs dead)
  __bf16* v16t = (__bf16*)(ws + 46 * MB);        // 46-54
  __bf16* qhi = (__bf16*)(ws + 54 * MB);         // 54-62
  __bf16* qlo = (__bf16*)(ws + 62 * MB);         // 62-70
  __bf16* khi = (__bf16*)(ws + 70 * MB);         // 70-78
  __bf16* klo = (__bf16*)(ws + 78 * MB);         // 78-86
  __bf16* wob = (__bf16*)(ws + 86 * MB);         // 86-88
  float* pm = (float*)(ws + 88 * MB);            // 88-88.72
  float* pl_ = (float*)(ws + 88 * MB + 768 * KB);
  float2* cs = (float2*)(ws + 89 * MB + 512 * KB);  // 256 KB
  __bf16* x16 = (__bf16*)(ws + 54 * MB);         // alias qhi (dead after k_attn)

  k_prep<<<8320, 256, 0, stream>>>((const float4*)query, (ushort4*)xh, (ushort4*)xl,
                                   (const float4*)win, (ushort4*)whh, (ushort4*)whl,
                                   (const float4*)wout, (ushort4*)wob, cs);

  // merged q,k,v projections (round-8/12/14 proven optimum)
  k_proj<<<1024, 256, 0, stream>>>(xh, xl, whh, whl, cs, qhi, qlo, khi, klo, v16t);

  // causal flash attention (XCD-swizzled flat grid)
  k_attn<<<512, 512, 0, stream>>>(qhi, qlo, khi, klo, v16t, x16, po, pm, pl_);

  // combine (XCD-aligned to attn's panel map)
  k_combine<<<14336, 256, 0, stream>>>(po, pm, pl_, x16);

  // out projection (32x128 tiles, grid 1024 -> 4 blocks/CU)
  k_gemmout<<<1024, 256, 0, stream>>>(x16, wob, out);
}

// Round 17
// 185.901 us; speedup vs baseline: 1.0770x; 1.0016x over previous
//
#include <hip/hip_runtime.h>
#include <stdint.h>

#define T_ 2048
#define E_ 1024

typedef __attribute__((ext_vector_type(8))) __bf16 bf16x8;
typedef __attribute__((ext_vector_type(4))) float f32x4;

__device__ __forceinline__ void gload_lds16(const void* g, void* l) {
  __builtin_amdgcn_global_load_lds(
      (const __attribute__((address_space(1))) unsigned int*)g,
      (__attribute__((address_space(3))) unsigned int*)l, 16, 0, 0);
}

// ---------------- fused prep: hi/lo splits + wout cvt + cos/sin table ----------------
// NOTE (R13): in_proj weights MUST keep the hi/lo split (q,k are O(30-100),
// scores O(100); dropping Xh*Wl -> O(1) absolute score error -> exp blows it up).
__global__ __launch_bounds__(256) void k_prep(const float4* __restrict__ q,
                                              ushort4* __restrict__ xh,
                                              ushort4* __restrict__ xl,
                                              const float4* __restrict__ win,
                                              ushort4* __restrict__ whh,
                                              ushort4* __restrict__ whl,
                                              const float4* __restrict__ wout,
                                              ushort4* __restrict__ wob,
                                              float2* __restrict__ cs) {
  const int b = blockIdx.x, tid = threadIdx.x;
  if (b < 7168) {  // hi/lo split: query (4096 blocks) then in_proj weights (3072)
    const float4* src;
    ushort4 *hi, *lo;
    int i;
    if (b < 4096) { src = q; hi = xh; lo = xl; i = b * 256 + tid; }
    else          { src = win; hi = whh; lo = whl; i = (b - 4096) * 256 + tid; }
    float4 x = src[i];
    float xs[4] = {x.x, x.y, x.z, x.w};
    union { __bf16 bb[4]; ushort4 u; } H, L;
#pragma unroll
    for (int jj = 0; jj < 4; ++jj) {
      __bf16 h = (__bf16)xs[jj];
      H.bb[jj] = h;
      L.bb[jj] = (__bf16)(xs[jj] - (float)h);
    }
    hi[i] = H.u;
    lo[i] = L.u;
  } else if (b < 8192) {  // wout plain cvt (1024 blocks)
    int i = (b - 7168) * 256 + tid;
    float4 x = wout[i];
    float xs[4] = {x.x, x.y, x.z, x.w};
    union { __bf16 bb[4]; ushort4 u; } H;
#pragma unroll
    for (int jj = 0; jj < 4; ++jj) H.bb[jj] = (__bf16)xs[jj];
    wob[i] = H.u;
  } else {  // cos/sin table, double precision (128 blocks)
    int i = (b - 8192) * 256 + tid;
    int t = i >> 4, f = i & 15;
    double inv = pow(10000.0, -(double)f / 16.0);
    double ang = (double)t * inv;
    cs[i] = make_float2((float)cos(ang), (float)sin(ang));
  }
}

// ---------------- merged projections: qk (blocks 0..511) + v (blocks 512..1023) ----
// ROUND-8/12/14 PROVEN OPTIMUM (76.4us, 898 TF ~ m97-class 2-barrier ceiling).
// Closed ledger of failed attacks: R9 512-thr (spill), R10 BK=32 single-buf
// (2x drains), R11 128x64 tiles (2x A-traffic), R13 2-term (correctness),
// R15 BK=32 dbuf (2x barrier drains). Do not re-tile.
__global__ __launch_bounds__(256) void k_proj(const __bf16* __restrict__ xh,
                                              const __bf16* __restrict__ xl,
                                              const __bf16* __restrict__ whh,
                                              const __bf16* __restrict__ whl,
                                              const float2* __restrict__ cs,
                                              __bf16* __restrict__ qhi,
                                              __bf16* __restrict__ qlo,
                                              __bf16* __restrict__ khi,
                                              __bf16* __restrict__ klo,
                                              __bf16* __restrict__ v16t) {
  __shared__ __align__(16) __bf16 AsH[128 * 64];
  __shared__ __align__(16) __bf16 BsH[128 * 64];
  __shared__ __align__(16) __bf16 AsL[128 * 64];
  __shared__ __align__(16) __bf16 BsL[128 * 64];
  const int tid = threadIdx.x, lane = tid & 63, w = tid >> 6;
  const int g = lane >> 4, d = lane & 15;
  const int lr8 = lane >> 3;
  const int swz8 = ((lane & 7) ^ lr8) * 8;
  const int rsl = d & 7;
  const int K = 1024;

  if (blockIdx.x < 512) {  // ---- qk path ----
    const int bi = blockIdx.x;                  // i = (y>>2) + 8*x + 128*(y&3)
    const int bx = (bi >> 3) & 15;
    const int by = ((bi & 7) << 2) | ((bi >> 7) & 3);
    const int wm = w >> 1, wn = w & 1;
    const int m0 = by * 128, n0 = bx * 128;

    f32x4 acc[4][4];
#pragma unroll
    for (int i = 0; i < 4; ++i)
#pragma unroll
      for (int j = 0; j < 4; ++j) acc[i][j] = (f32x4)(0.0f);

    for (int k0 = 0; k0 < K; k0 += 64) {
      __syncthreads();
#pragma unroll
      for (int c = 0; c < 4; ++c) {
        const int rr = c * 32 + w * 8 + lr8;
        const int ldo = (c * 32 + w * 8) * 64;
        gload_lds16(xh + (size_t)(m0 + rr) * K + k0 + swz8, &AsH[ldo]);
        gload_lds16(xl + (size_t)(m0 + rr) * K + k0 + swz8, &AsL[ldo]);
        gload_lds16(whh + (size_t)(n0 + rr) * K + k0 + swz8, &BsH[ldo]);
        gload_lds16(whl + (size_t)(n0 + rr) * K + k0 + swz8, &BsL[ldo]);
      }
      __syncthreads();
#pragma unroll
      for (int k2 = 0; k2 < 2; ++k2) {
        const int sl = ((k2 * 4 + g) ^ rsl) * 8;
        bf16x8 bh[4], bl[4];
#pragma unroll
        for (int j = 0; j < 4; ++j) {
          const int r = wn * 64 + j * 16 + d;
          bh[j] = *(const bf16x8*)&BsH[r * 64 + sl];
          bl[j] = *(const bf16x8*)&BsL[r * 64 + sl];
        }
#pragma unroll
        for (int i = 0; i < 4; ++i) {
          const int r = wm * 64 + i * 16 + d;
          const bf16x8 ahf = *(const bf16x8*)&AsH[r * 64 + sl];
          const bf16x8 alf = *(const bf16x8*)&AsL[r * 64 + sl];
#pragma unroll
          for (int j = 0; j < 4; ++j) {
            acc[i][j] = __builtin_amdgcn_mfma_f32_16x16x32_bf16(ahf, bh[j], acc[i][j], 0, 0, 0);
            acc[i][j] = __builtin_amdgcn_mfma_f32_16x16x32_bf16(alf, bh[j], acc[i][j], 0, 0, 0);
            acc[i][j] = __builtin_amdgcn_mfma_f32_16x16x32_bf16(ahf, bl[j], acc[i][j], 0, 0, 0);
          }
        }
      }
    }

#pragma unroll
    for (int i = 0; i < 4; ++i) {
      const int rbase = m0 + (w >> 1) * 64 + i * 16 + g * 4;
#pragma unroll
      for (int j = 0; j < 4; ++j) {
        const int col = n0 + (w & 1) * 64 + j * 16 + d;
#pragma unroll
        for (int r = 0; r < 4; ++r) {
          const float vv = acc[i][j][r];
          const int row = rbase + r;
          // RoPE pair partner (cl^1) lives at lane^1, same fragment reg
          const float xp = __shfl_xor(vv, 1);
          const int which = col >> 10;  // 0=q, 1=k
          const int cl = col & 1023;
          const int d2 = cl & 63;
          const int t2 = (row & 127) * 16 + (cl >> 6);  // reshaped position
          float y;
          if (d2 < 32) {
            const float2 cse = cs[t2 * 16 + (d2 >> 1)];
            y = (d2 & 1) ? (vv * cse.x + xp * cse.y) : (vv * cse.x - xp * cse.y);
          } else {
            y = vv;
          }
          if (which == 0) y *= 0.18033688011112042f;  // log2(e)/8: log2-domain scores
          const __bf16 hi = (__bf16)y;
          const __bf16 lo = (__bf16)(y - (float)hi);
          const size_t off = (size_t)row * 1024 + cl;  // flat == [panel][t2][d2]
          (which ? khi : qhi)[off] = hi;
          (which ? klo : qlo)[off] = lo;
        }
      }
    }
  } else {  // ---- v path (uses AsH as As, BsH as Bs) ----
    const int bi = blockIdx.x - 512;            // i = (y>>3) + 8*x + 64*(y&7)
    const int bx = (bi >> 3) & 7;
    const int by = ((bi & 7) << 3) | ((bi >> 6) & 7);
    const int m0 = by * 64, n0 = bx * 128;
    const __bf16* Bv = whh + (size_t)2048 * 1024;

    f32x4 acc[4][2];
#pragma unroll
    for (int i = 0; i < 4; ++i)
#pragma unroll
      for (int j = 0; j < 2; ++j) acc[i][j] = (f32x4)(0.0f);

    for (int k0 = 0; k0 < K; k0 += 64) {
      __syncthreads();
#pragma unroll
      for (int c = 0; c < 2; ++c) {
        const int rr = c * 32 + w * 8 + lr8;
        gload_lds16(xh + (size_t)(m0 + rr) * K + k0 + swz8, &AsH[(c * 32 + w * 8) * 64]);
      }
#pragma unroll
      for (int c = 0; c < 4; ++c) {
        const int rr = c * 32 + w * 8 + lr8;
        gload_lds16(Bv + (size_t)(n0 + rr) * K + k0 + swz8, &BsH[(c * 32 + w * 8) * 64]);
      }
      __syncthreads();
#pragma unroll
      for (int k2 = 0; k2 < 2; ++k2) {
        const int sl = ((k2 * 4 + g) ^ rsl) * 8;
        bf16x8 bh[2], ah[4];
#pragma unroll
        for (int j = 0; j < 2; ++j)
          bh[j] = *(const bf16x8*)&BsH[(w * 32 + j * 16 + d) * 64 + sl];
#pragma unroll
        for (int i = 0; i < 4; ++i)
          ah[i] = *(const bf16x8*)&AsH[(i * 16 + d) * 64 + sl];
#pragma unroll
        for (int i = 0; i < 4; ++i)
#pragma unroll
          for (int j = 0; j < 2; ++j)
            acc[i][j] = __builtin_amdgcn_mfma_f32_16x16x32_bf16(ah[i], bh[j], acc[i][j], 0, 0, 0);
      }
    }

#pragma unroll
    for (int i = 0; i < 4; ++i) {
      const int rbase = m0 + i * 16 + g * 4;
#pragma unroll
      for (int j = 0; j < 2; ++j) {
        const int col = n0 + w * 32 + j * 16 + d;
#pragma unroll
        for (int r = 0; r < 4; ++r) {
          const int row = rbase + r;
          const int p = row >> 7;
          const int tp = ((row & 127) << 4) | (col >> 6);
          const int dp = col & 63;
          v16t[((size_t)p * 64 + dp) * 2048 + tp] = (__bf16)acc[i][j][r];
        }
      }
    }
  }
}

// ---------------- out projection GEMM, 32x128 tile, BK=64, grid 1024 ----------------
__global__ __launch_bounds__(256) void k_gemmout(const __bf16* __restrict__ Ah,
                                                 const __bf16* __restrict__ Bh,
                                                 float* __restrict__ C32) {
  __shared__ __align__(16) __bf16 As[32 * 64];
  __shared__ __align__(16) __bf16 Bs[128 * 64];
  const int bi = blockIdx.x;                    // bi = (by>>4) + 8*bx + 64*(by&15)
  const int bx = (bi >> 3) & 7;
  const int by = ((bi & 7) << 4) | (bi >> 6);
  const int tid = threadIdx.x, lane = tid & 63, w = tid >> 6;
  const int g = lane >> 4, d = lane & 15;
  const int m0 = by * 32, n0 = bx * 128;
  const int K = 1024, N = 1024;

  f32x4 acc[2][2];
#pragma unroll
  for (int i = 0; i < 2; ++i)
#pragma unroll
    for (int j = 0; j < 2; ++j) acc[i][j] = (f32x4)(0.0f);

  const int lr8 = lane >> 3;
  const int swz8 = ((lane & 7) ^ lr8) * 8;
  const int rsl = d & 7;

  for (int k0 = 0; k0 < K; k0 += 64) {
    __syncthreads();
    gload_lds16(Ah + (size_t)(m0 + w * 8 + lr8) * K + k0 + swz8, &As[(w * 8) * 64]);
#pragma unroll
    for (int c = 0; c < 4; ++c) {
      const int rr = c * 32 + w * 8 + lr8;
      gload_lds16(Bh + (size_t)(n0 + rr) * K + k0 + swz8, &Bs[(c * 32 + w * 8) * 64]);
    }
    __syncthreads();
#pragma unroll
    for (int k2 = 0; k2 < 2; ++k2) {
      const int sl = ((k2 * 4 + g) ^ rsl) * 8;
      bf16x8 bh[2], ah[2];
#pragma unroll
      for (int j = 0; j < 2; ++j)
        bh[j] = *(const bf16x8*)&Bs[(w * 32 + j * 16 + d) * 64 + sl];
#pragma unroll
      for (int i = 0; i < 2; ++i)
        ah[i] = *(const bf16x8*)&As[(i * 16 + d) * 64 + sl];
#pragma unroll
      for (int i = 0; i < 2; ++i)
#pragma unroll
        for (int j = 0; j < 2; ++j)
          acc[i][j] = __builtin_amdgcn_mfma_f32_16x16x32_bf16(ah[i], bh[j], acc[i][j], 0, 0, 0);
    }
  }

#pragma unroll
  for (int i = 0; i < 2; ++i) {
    const int rbase = m0 + i * 16 + g * 4;
#pragma unroll
    for (int j = 0; j < 2; ++j) {
      const int col = n0 + w * 32 + j * 16 + d;
#pragma unroll
      for (int r = 0; r < 4; ++r)
        C32[(size_t)(rbase + r) * N + col] = acc[i][j][r];
    }
  }
}

// ---------------- causal flash attention ----------------
// 512 thr / 8 waves; QBLK=256; KVBLK=64; double-buffered K/V, 1 barrier/tile.
// Equal-tile packing: 144 units/panel, 16 blocks x 9 units; <=2 segments/block;
// slot = b+qt (23/panel). Full-range segments (qt0) write x16 directly.
// XCD swizzle: panel%8 = i%8 (KV L2-resident, proven: FETCH 77->43MB).
// NEW (R17): po partials stored as BF16 (linear V-side path — same quantization
// class as the proven-safe v16t/x16 bf16 stores; no exp downstream). Halves the
// attn->combine HBM round-trip (~42MB -> ~21MB each way).
__global__ __launch_bounds__(512, 4) void k_attn(const __bf16* __restrict__ qhi,
                                                 const __bf16* __restrict__ qlo,
                                                 const __bf16* __restrict__ khi,
                                                 const __bf16* __restrict__ klo,
                                                 const __bf16* __restrict__ v16t,
                                                 __bf16* __restrict__ x16,
                                                 __bf16* __restrict__ po,
                                                 float* __restrict__ pm,
                                                 float* __restrict__ pl_) {
  __shared__ __align__(16) __bf16 KH[2][64 * 64];
  __shared__ __align__(16) __bf16 KL[2][64 * 64];
  __shared__ __align__(16) __bf16 VT[2][64 * 64];
  __shared__ __align__(16) __bf16 PL[8][16 * 72];

  const int bi = blockIdx.x;                    // i = (panel&7) + 8*b + 128*(panel>>3)
  const int b = (bi >> 3) & 15;
  const int panel = (bi & 7) | (((bi >> 7) & 3) << 3);
  const int u0 = 9 * b;
  int qtA = 0;
  while (2 * (qtA + 1) * (qtA + 2) <= u0) ++qtA;
  const int cumA = 2 * qtA * (qtA + 1);
  const int cumB = 2 * (qtA + 1) * (qtA + 2);
  const int jloA = u0 - cumA;
  const bool two = (u0 + 9 > cumB);
  const int jhiA = two ? (cumB - 1 - cumA) : (u0 + 8 - cumA);
  const int jhiB = u0 + 8 - cumB;  // valid only if two

  const int tid = threadIdx.x, lane = tid & 63, w = tid >> 6;
  const int g = lane >> 4, d = lane & 15;
  const size_t hb = (size_t)panel * T_ * 64;

  const int kr = tid >> 3, kc = tid & 7;
  const int swz = (kc ^ (kr & 7)) * 8;
  const __bf16* kB = khi + hb;
  const __bf16* lB = klo + hb;
  const __bf16* vB = v16t + (size_t)panel * (64 * T_);

#define STAGE(j, bb)                                                        \
  {                                                                         \
    gload_lds16(kB + (size_t)((j) * 64 + kr) * 64 + swz, &KH[bb][w * 512]); \
    gload_lds16(lB + (size_t)((j) * 64 + kr) * 64 + swz, &KL[bb][w * 512]); \
    gload_lds16(vB + (size_t)kr * T_ + (j) * 64 + swz, &VT[bb][w * 512]);   \
  }

  int cur = 0;
  STAGE(jloA, 0);

  for (int seg = 0; seg < 2; ++seg) {
    if (seg && !two) break;
    const int qt = qtA + seg;
    const int jlo = seg ? 0 : jloA;
    const int jhi = seg ? jhiB : jhiA;
    const int q0 = qt << 8;

    bf16x8 qh[2][2], ql[2][2];
#pragma unroll
    for (int rb = 0; rb < 2; ++rb) {
      const int rbi = w * 2 + rb;
      const size_t qrow = hb + (size_t)(q0 + rbi * 16 + d) * 64;
      qh[rb][0] = *(const bf16x8*)&qhi[qrow + g * 8];
      qh[rb][1] = *(const bf16x8*)&qhi[qrow + 32 + g * 8];
      ql[rb][0] = *(const bf16x8*)&qlo[qrow + g * 8];
      ql[rb][1] = *(const bf16x8*)&qlo[qrow + 32 + g * 8];
    }

    f32x4 o[2][4];
#pragma unroll
    for (int rb = 0; rb < 2; ++rb)
#pragma unroll
      for (int i = 0; i < 4; ++i) o[rb][i] = (f32x4)(0.0f);
    float m_[2] = {-__builtin_inff(), -__builtin_inff()};
    float l_[2] = {0.0f, 0.0f};

    for (int j = jlo; j <= jhi; ++j) {
      __syncthreads();  // drains prefetch into buf[cur]; frees buf[cur^1]
      if (j < jhi) {
        STAGE(j + 1, cur ^ 1);
      } else if (!seg && two) {
        STAGE(0, cur ^ 1);  // cross-segment prefetch (K/V depend only on j)
      }

#pragma unroll
      for (int rb = 0; rb < 2; ++rb) {
        const int rbi = w * 2 + rb;
        const int qrow0 = q0 + rbi * 16;
        if (j * 64 > qrow0 + 15) continue;  // fully masked rb: skip (partials stay safe)

        f32x4 s[4];
        __builtin_amdgcn_s_setprio(1);
#pragma unroll
        for (int f = 0; f < 4; ++f) {
          f32x4 accs = (f32x4)(0.0f);
          const int colr = f * 16 + d;
#pragma unroll
          for (int ds = 0; ds < 2; ++ds) {
            const int slot = ((ds * 4 + g) ^ (colr & 7)) * 8;
            const bf16x8 kf = *(const bf16x8*)&KH[cur][colr * 64 + slot];
            const bf16x8 lf = *(const bf16x8*)&KL[cur][colr * 64 + slot];
            // SWAPPED: S^T[kv][q] — K is the A-operand, Q the B-operand
            accs = __builtin_amdgcn_mfma_f32_16x16x32_bf16(kf, qh[rb][ds], accs, 0, 0, 0);
            accs = __builtin_amdgcn_mfma_f32_16x16x32_bf16(kf, ql[rb][ds], accs, 0, 0, 0);
            accs = __builtin_amdgcn_mfma_f32_16x16x32_bf16(lf, qh[rb][ds], accs, 0, 0, 0);
          }
          s[f] = accs;
        }
        __builtin_amdgcn_s_setprio(0);

        if (j * 64 + 63 > qrow0) {  // diagonal-crossing tile: mask kv > q
          const int qq = qrow0 + d;
#pragma unroll
          for (int f = 0; f < 4; ++f)
#pragma unroll
            for (int r = 0; r < 4; ++r) {
              const int kv = j * 64 + f * 16 + g * 4 + r;
              if (kv > qq) s[f][r] = -30000.0f;  // sentinel (log2 domain), NaN-safe
            }
        }

        // in-register softmax: lane owns q-row d; reduce in-lane + across g
        float pmax = fmaxf(fmaxf(s[0][0], s[0][1]), fmaxf(s[0][2], s[0][3]));
#pragma unroll
        for (int f = 1; f < 4; ++f)
          pmax = fmaxf(pmax, fmaxf(fmaxf(s[f][0], s[f][1]), fmaxf(s[f][2], s[f][3])));
        pmax = fmaxf(pmax, __shfl_xor(pmax, 16));
        pmax = fmaxf(pmax, __shfl_xor(pmax, 32));

        if (!__all(pmax - m_[rb] <= 11.5f)) {  // defer-max: rescale only on real growth
          const float mnew = fmaxf(m_[rb], pmax);
          const float fac = exp2f(m_[rb] - mnew);
          m_[rb] = mnew;
          float facr[4];
#pragma unroll
          for (int r = 0; r < 4; ++r)
            facr[r] = __shfl(fac, (lane & 48) | (g * 4 + r));  // fac for o-row g*4+r
#pragma unroll
          for (int ni = 0; ni < 4; ++ni)
#pragma unroll
            for (int r = 0; r < 4; ++r) o[rb][ni][r] *= facr[r];
          l_[rb] *= fac;
        }

        float sum = 0.0f;
#pragma unroll
        for (int f = 0; f < 4; ++f) {
          union { __bf16 bb[4]; ushort4 u4; } pk;
#pragma unroll
          for (int r = 0; r < 4; ++r) {
            const float pv = exp2f(s[f][r] - m_[rb]);
            sum += pv;
            pk.bb[r] = (__bf16)pv;
          }
          // P[q=d][kv=f*16+g*4 .. +4] packed: one ds_write_b64
          *(ushort4*)&PL[w][d * 72 + f * 16 + g * 4] = pk.u4;
        }
        sum += __shfl_xor(sum, 16);
        sum += __shfl_xor(sum, 32);
        l_[rb] += sum;

        __builtin_amdgcn_s_setprio(1);
#pragma unroll
        for (int ks = 0; ks < 2; ++ks) {
          const bf16x8 pa = *(const bf16x8*)&PL[w][d * 72 + ks * 32 + g * 8];
#pragma unroll
          for (int ni = 0; ni < 4; ++ni) {
            const bf16x8 vf =
                *(const bf16x8*)&VT[cur][(ni * 16 + d) * 64 + (((ks * 4 + g) ^ (d & 7)) * 8)];
            o[rb][ni] = __builtin_amdgcn_mfma_f32_16x16x32_bf16(pa, vf, o[rb][ni], 0, 0, 0);
          }
        }
        __builtin_amdgcn_s_setprio(0);
      }
      cur ^= 1;
    }

    if (jlo == 0 && jhi == 4 * qt + 3) {
      // segment covers the q-tile's full kv range: final write, no partials.
#pragma unroll
      for (int rb = 0; rb < 2; ++rb) {
        const int rbi = w * 2 + rb;
        float lr[4];
#pragma unroll
        for (int r = 0; r < 4; ++r)
          lr[r] = __shfl(l_[rb], (lane & 48) | (g * 4 + r));
#pragma unroll
        for (int ni = 0; ni < 4; ++ni)
#pragma unroll
          for (int r = 0; r < 4; ++r) {
            const size_t row = hb + (size_t)(q0 + rbi * 16 + g * 4 + r) * 64;
            x16[row + ni * 16 + d] = (__bf16)(o[rb][ni][r] / lr[r]);
          }
      }
    } else {
      const int slot = panel * 23 + b + qt;
#pragma unroll
      for (int rb = 0; rb < 2; ++rb) {
        const int rbi = w * 2 + rb;
#pragma unroll
        for (int ni = 0; ni < 4; ++ni)
#pragma unroll
          for (int r = 0; r < 4; ++r) {
            const int rowin = rbi * 16 + g * 4 + r;
            po[(size_t)slot * 16384 + rowin * 64 + ni * 16 + d] = (__bf16)o[rb][ni][r];
          }
        if (g == 0) {  // lane owns q-row d: one write per row
          pm[slot * 256 + rbi * 16 + d] = m_[rb];
          pl_[slot * 256 + rbi * 16 + d] = l_[rb];
        }
      }
    }
  }
#undef STAGE
}

// ---------------- merge KV-chunk partials for rows 256..2047 (log2 domain) ----------------
// 1D grid 14336, XCD-aligned: panel%8 == bi%8 matches attn's panel->XCD map so
// po/pm/pl reads hit the L2 that produced them. po is BF16 (R17).
__global__ __launch_bounds__(256) void k_combine(const __bf16* __restrict__ po,
                                                 const float* __restrict__ pm,
                                                 const float* __restrict__ pl_,
                                                 __bf16* __restrict__ x16) {
  const int bi = blockIdx.x;                      // 8 * 448 * 4
  const int p = (bi & 7) | ((bi / 3584) << 3);
  const int li = ((bi >> 3) % 448) * 256 + threadIdx.x;
  const int d = li & 63;
  const int t2 = 256 + (li >> 6);
  const int qt = t2 >> 8;                          // 1..7
  const int rowin = t2 & 255;
  const int cq = 2 * qt * (qt + 1);
  const int nc = (cq + 4 * qt + 3) / 9 - cq / 9 + 1;
  const int s0 = p * 23 + cq / 9 + qt;
  float M = -__builtin_inff();
  for (int s = 0; s < nc; ++s) M = fmaxf(M, pm[(s0 + s) * 256 + rowin]);
  float L = 0.0f, O = 0.0f;
  for (int s = 0; s < nc; ++s) {
    const float ww = exp2f(pm[(s0 + s) * 256 + rowin] - M);
    L += pl_[(s0 + s) * 256 + rowin] * ww;
    O += (float)po[(size_t)(s0 + s) * 16384 + rowin * 64 + d] * ww;
  }
  x16[((size_t)p * T_ + t2) * 64 + d] = (__bf16)(O / L);
}

extern "C" void kernel_launch(void* const* d_in, const int* in_sizes, int n_in,
                              void* d_out, int out_size, void* d_ws, size_t ws_size,
                              hipStream_t stream) {
  const float* query = (const float*)d_in[0];
  const float* win = (const float*)d_in[4];
  const float* wout = (const float*)d_in[5];
  float* out = (float*)d_out;

  const size_t MB = 1024 * 1024;
  const size_t KB = 1024;
  char* ws = (char*)d_ws;
  // Lifetime plan: prep buffers (0-28) die after k_proj; po (attn-write, BF16 now
  // 23MB) overlays them at 0-23. v16t at 46-54. Peak usage 89.75 MB.
  __bf16* xh = (__bf16*)(ws);                    // 0-8
  __bf16* xl = (__bf16*)(ws + 8 * MB);           // 8-16
  __bf16* whh = (__bf16*)(ws + 16 * MB);         // 16-22
  __bf16* whl = (__bf16*)(ws + 22 * MB);         // 22-28
  __bf16* po = (__bf16*)(ws);                    // 0-23 (attn-write, prep bufs dead)
  __bf16* v16t = (__bf16*)(ws + 46 * MB);        // 46-54
  __bf16* qhi = (__bf16*)(ws + 54 * MB);         // 54-62
  __bf16* qlo = (__bf16*)(ws + 62 * MB);         // 62-70
  __bf16* khi = (__bf16*)(ws + 70 * MB);         // 70-78
  __bf16* klo = (__bf16*)(ws + 78 * MB);         // 78-86
  __bf16* wob = (__bf16*)(ws + 86 * MB);         // 86-88
  float* pm = (float*)(ws + 88 * MB);            // 88-88.72
  float* pl_ = (float*)(ws + 88 * MB + 768 * KB);
  float2* cs = (float2*)(ws + 89 * MB + 512 * KB);  // 256 KB
  __bf16* x16 = (__bf16*)(ws + 54 * MB);         // alias qhi (dead after k_attn)

  k_prep<<<8320, 256, 0, stream>>>((const float4*)query, (ushort4*)xh, (ushort4*)xl,
                                   (const float4*)win, (ushort4*)whh, (ushort4*)whl,
                                   (const float4*)wout, (ushort4*)wob, cs);

  // merged q,k,v projections (round-8/12/14 proven optimum)
  k_proj<<<1024, 256, 0, stream>>>(xh, xl, whh, whl, cs, qhi, qlo, khi, klo, v16t);

  // causal flash attention (XCD-swizzled flat grid; bf16 po partials)
  k_attn<<<512, 512, 0, stream>>>(qhi, qlo, khi, klo, v16t, x16, po, pm, pl_);

  // combine (XCD-aligned to attn's panel map)
  k_combine<<<14336, 256, 0, stream>>>(po, pm, pl_, x16);

  // out projection (32x128 tiles, grid 1024 -> 4 blocks/CU)
  k_gemmout<<<1024, 256, 0, stream>>>(x16, wob, out);
}